// Round 1
// 338.513 us; speedup vs baseline: 1.0782x; 1.0782x over previous
//
#include <hip/hip_runtime.h>

// MiniTransformer: B=131072, T=8, D=32, H=64, V=27  (all f32, out f32)
// R7: LDS-staged weights + float4 ds_read restructure of MLP/Wout.
//   R6 post-mortem: fused_main VALUBusy 56% at 240us; ~15.8k VALU instr/wave
//   vs ~5.4k FMA => per-scalar-weight-load address arithmetic (~5k loads x
//   2 VALU of 64-bit addr calc) is the dominant overhead. Fix: W1/W2/WoT in
//   LDS (19.8KB), all weight reads become ds_read_b128 with immediate
//   offsets; LN/softmax reductions go 4-accumulator tree to cut dependent
//   chain latency. Gather remapped to contiguous 81-float runs per b.

namespace {
constexpr int BTOT = 131072;     // 2^17
constexpr int T = 8;
constexpr int D = 32;
constexpr int H = 64;
constexpr int V = 27;
constexpr int NTOK = 27;
constexpr int NROW = T * NTOK;   // 216
constexpr float EPS = 1e-5f;

// ws layout (float offsets)
constexpr int WS_X  = 0;             // 216*32
constexpr int WS_Q  = 6912;
constexpr int WS_K  = 13824;
constexpr int WS_V  = 20736;
constexpr int WS_SC = 27648;         // 216*216 = 46656
constexpr int NSC   = NROW * NROW;
constexpr int WS_P  = WS_SC + NSC;   // 74304: prefix-output tables
constexpr int NPRE0 = 27;
constexpr int NPRE1 = 729;
constexpr int NPRE2 = 19683;
constexpr int NPRE  = NPRE0 + NPRE1 + NPRE2;   // 20439
constexpr size_t WS_NEED_BIG = (size_t)(WS_P + NPRE * V) * 4;  // ~2.45 MB

constexpr int MAIN_BLOCKS = (5 * BTOT) / 256;          // 2560, exact
constexpr int PRE_BLOCKS  = (NPRE + 255) / 256;        // 80
} // namespace

// ---- kernel A: X/Q/K/V row tables, thread per (row,d) ----
__global__ __launch_bounds__(256) void build_rows_kernel(
    const float* __restrict__ tokE, const float* __restrict__ posE,
    const float* __restrict__ Wq, const float* __restrict__ Wk,
    const float* __restrict__ Wv, float* __restrict__ ws) {
  const int idx = blockIdx.x * 256 + threadIdx.x;
  if (idx >= NROW * D) return;
  const int row = idx >> 5, d = idx & 31;
  const int t = row / NTOK, tok = row % NTOK;
  float x[D];
#pragma unroll
  for (int g = 0; g < D / 4; ++g) {
    const float4 a = *(const float4*)(tokE + tok * D + 4 * g);
    const float4 c = *(const float4*)(posE + t * D + 4 * g);
    x[4 * g + 0] = a.x + c.x;
    x[4 * g + 1] = a.y + c.y;
    x[4 * g + 2] = a.z + c.z;
    x[4 * g + 3] = a.w + c.w;
  }
  float aq = 0.f, ak = 0.f, av = 0.f;
#pragma unroll
  for (int k = 0; k < D; ++k) {
    const float xv = x[k];
    aq = fmaf(xv, Wq[k * D + d], aq);
    ak = fmaf(xv, Wk[k * D + d], ak);
    av = fmaf(xv, Wv[k * D + d], av);
  }
  ws[WS_X + row * D + d] = x[d];
  ws[WS_Q + row * D + d] = aq;
  ws[WS_K + row * D + d] = ak;
  ws[WS_V + row * D + d] = av;
}

// ---- kernel B: score table SC[(t*27+tokt)*216 + s*27+toks] ----
__global__ __launch_bounds__(256) void build_sc_kernel(float* __restrict__ ws) {
  const int i = blockIdx.x * 256 + threadIdx.x;
  if (i >= NSC) return;
  const int qrow = i / NROW;
  const int j    = i - qrow * NROW;
  const float4* q = (const float4*)(ws + WS_Q + qrow * D);
  const float4* k = (const float4*)(ws + WS_K + j * D);
  float a = 0.f;
#pragma unroll
  for (int g = 0; g < D / 4; ++g) {
    const float4 qa = q[g], ka = k[g];
    a = fmaf(qa.x, ka.x, a);
    a = fmaf(qa.y, ka.y, a);
    a = fmaf(qa.z, ka.z, a);
    a = fmaf(qa.w, ka.w, a);
  }
  ws[WS_SC + i] = a;
}

// ---- shared row computation (weights come from LDS) ----
__device__ __forceinline__ void compute_row(
    const int t, const int* toks,
    const float* __restrict__ ws,
    const float* sW1, const float* sW2, const float* sWoT,
    float* __restrict__ dst) {
  const int tok_t = toks[t];
  const float* SC = ws + WS_SC + (t * NTOK + tok_t) * NROW;
  float sc[T];
#pragma unroll
  for (int s = 0; s < T; ++s)
    sc[s] = (s <= t) ? SC[s * NTOK + toks[s]] : -INFINITY;

  // tree max (depth 3 instead of serial depth 7)
  const float m01 = fmaxf(sc[0], sc[1]), m23 = fmaxf(sc[2], sc[3]);
  const float m45 = fmaxf(sc[4], sc[5]), m67 = fmaxf(sc[6], sc[7]);
  const float mx = fmaxf(fmaxf(m01, m23), fmaxf(m45, m67));

  float p[T];
  float den0 = 0.f, den1 = 0.f;
#pragma unroll
  for (int s = 0; s < T; s += 2) {
    p[s]     = (s     <= t) ? __expf(sc[s]     - mx) : 0.f;
    p[s + 1] = (s + 1 <= t) ? __expf(sc[s + 1] - mx) : 0.f;
    den0 += p[s];
    den1 += p[s + 1];
  }
  const float inv = 1.f / (den0 + den1);

  float o[D];
#pragma unroll
  for (int d = 0; d < D; ++d) o[d] = 0.f;
#pragma unroll
  for (int s = 0; s < T; ++s) {
    if (s <= t) {
      const float4* vr = (const float4*)(ws + WS_V + (s * NTOK + toks[s]) * D);
      const float ps = p[s];
#pragma unroll
      for (int g = 0; g < D / 4; ++g) {
        const float4 v4 = vr[g];
        o[4 * g + 0] = fmaf(ps, v4.x, o[4 * g + 0]);
        o[4 * g + 1] = fmaf(ps, v4.y, o[4 * g + 1]);
        o[4 * g + 2] = fmaf(ps, v4.z, o[4 * g + 2]);
        o[4 * g + 3] = fmaf(ps, v4.w, o[4 * g + 3]);
      }
    }
  }
  {
    const float4* xr = (const float4*)(ws + WS_X + (t * NTOK + tok_t) * D);
#pragma unroll
    for (int g = 0; g < D / 4; ++g) {
      const float4 x4 = xr[g];
      o[4 * g + 0] = fmaf(o[4 * g + 0], inv, x4.x);
      o[4 * g + 1] = fmaf(o[4 * g + 1], inv, x4.y);
      o[4 * g + 2] = fmaf(o[4 * g + 2], inv, x4.z);
      o[4 * g + 3] = fmaf(o[4 * g + 3], inv, x4.w);
    }
  }

  // LayerNorm 1 (4-accumulator tree reductions)
  {
    float s1a = 0.f, s1b = 0.f, s1c = 0.f, s1d = 0.f;
#pragma unroll
    for (int d = 0; d < D; d += 4) {
      s1a += o[d]; s1b += o[d + 1]; s1c += o[d + 2]; s1d += o[d + 3];
    }
    const float mean = ((s1a + s1b) + (s1c + s1d)) * (1.f / D);
    float q0 = 0.f, q1 = 0.f, q2 = 0.f, q3 = 0.f;
#pragma unroll
    for (int d = 0; d < D; d += 4) {
      const float c0 = o[d] - mean, c1 = o[d + 1] - mean;
      const float c2 = o[d + 2] - mean, c3 = o[d + 3] - mean;
      q0 = fmaf(c0, c0, q0); q1 = fmaf(c1, c1, q1);
      q2 = fmaf(c2, c2, q2); q3 = fmaf(c3, c3, q3);
    }
    const float rr = rsqrtf(((q0 + q1) + (q2 + q3)) * (1.f / D) + EPS);
#pragma unroll
    for (int d = 0; d < D; ++d) o[d] = (o[d] - mean) * rr;
  }

  // MLP: weights from LDS, all reads ds_read_b128 w/ immediate offsets
  float y[D];
#pragma unroll
  for (int d = 0; d < D; ++d) y[d] = 0.f;
#pragma unroll
  for (int jc = 0; jc < H / 16; ++jc) {
    float hh[16];
#pragma unroll
    for (int jj = 0; jj < 16; ++jj) hh[jj] = 0.f;
#pragma unroll
    for (int d = 0; d < D; ++d) {
      const float od = o[d];
      const float4* wr = (const float4*)(sW1 + d * H + jc * 16);
      const float4 w0 = wr[0], w1 = wr[1], w2 = wr[2], w3 = wr[3];
      hh[0]  = fmaf(od, w0.x, hh[0]);  hh[1]  = fmaf(od, w0.y, hh[1]);
      hh[2]  = fmaf(od, w0.z, hh[2]);  hh[3]  = fmaf(od, w0.w, hh[3]);
      hh[4]  = fmaf(od, w1.x, hh[4]);  hh[5]  = fmaf(od, w1.y, hh[5]);
      hh[6]  = fmaf(od, w1.z, hh[6]);  hh[7]  = fmaf(od, w1.w, hh[7]);
      hh[8]  = fmaf(od, w2.x, hh[8]);  hh[9]  = fmaf(od, w2.y, hh[9]);
      hh[10] = fmaf(od, w2.z, hh[10]); hh[11] = fmaf(od, w2.w, hh[11]);
      hh[12] = fmaf(od, w3.x, hh[12]); hh[13] = fmaf(od, w3.y, hh[13]);
      hh[14] = fmaf(od, w3.z, hh[14]); hh[15] = fmaf(od, w3.w, hh[15]);
    }
#pragma unroll
    for (int jj = 0; jj < 16; ++jj) {
      const float hv = fmaxf(hh[jj], 0.f);
      const float4* wr = (const float4*)(sW2 + (jc * 16 + jj) * D);
#pragma unroll
      for (int g = 0; g < 8; ++g) {
        const float4 w = wr[g];
        y[4 * g + 0] = fmaf(hv, w.x, y[4 * g + 0]);
        y[4 * g + 1] = fmaf(hv, w.y, y[4 * g + 1]);
        y[4 * g + 2] = fmaf(hv, w.z, y[4 * g + 2]);
        y[4 * g + 3] = fmaf(hv, w.w, y[4 * g + 3]);
      }
    }
  }

  // residual + LayerNorm 2
#pragma unroll
  for (int d = 0; d < D; ++d) y[d] += o[d];
  {
    float s1a = 0.f, s1b = 0.f, s1c = 0.f, s1d = 0.f;
#pragma unroll
    for (int d = 0; d < D; d += 4) {
      s1a += y[d]; s1b += y[d + 1]; s1c += y[d + 2]; s1d += y[d + 3];
    }
    const float mean = ((s1a + s1b) + (s1c + s1d)) * (1.f / D);
    float q0 = 0.f, q1 = 0.f, q2 = 0.f, q3 = 0.f;
#pragma unroll
    for (int d = 0; d < D; d += 4) {
      const float c0 = y[d] - mean, c1 = y[d + 1] - mean;
      const float c2 = y[d + 2] - mean, c3 = y[d + 3] - mean;
      q0 = fmaf(c0, c0, q0); q1 = fmaf(c1, c1, q1);
      q2 = fmaf(c2, c2, q2); q3 = fmaf(c3, c3, q3);
    }
    const float rr = rsqrtf(((q0 + q1) + (q2 + q3)) * (1.f / D) + EPS);
#pragma unroll
    for (int d = 0; d < D; ++d) y[d] = (y[d] - mean) * rr;
  }

  // output projection from transposed Wout in LDS (row-contiguous reads)
#pragma unroll
  for (int v = 0; v < V; ++v) {
    const float4* wr = (const float4*)(sWoT + v * D);
    float a0 = 0.f, a1 = 0.f, a2 = 0.f, a3 = 0.f;
#pragma unroll
    for (int g = 0; g < 8; ++g) {
      const float4 w = wr[g];
      a0 = fmaf(y[4 * g + 0], w.x, a0);
      a1 = fmaf(y[4 * g + 1], w.y, a1);
      a2 = fmaf(y[4 * g + 2], w.z, a2);
      a3 = fmaf(y[4 * g + 3], w.w, a3);
    }
    dst[v] = (a0 + a1) + (a2 + a3);
  }
}

// ---- weight staging into LDS (all threads participate) ----
__device__ __forceinline__ void stage_weights(
    const float* __restrict__ W1, const float* __restrict__ W2,
    const float* __restrict__ Wo,
    float* sW1, float* sW2, float* sWoT) {
  const int tid = threadIdx.x;
#pragma unroll
  for (int i = tid; i < (D * H) / 4; i += 256)
    ((float4*)sW1)[i] = ((const float4*)W1)[i];
#pragma unroll
  for (int i = tid; i < (H * D) / 4; i += 256)
    ((float4*)sW2)[i] = ((const float4*)W2)[i];
  for (int i = tid; i < V * D; i += 256) {
    const int v = i >> 5, d = i & 31;           // i = v*32 + d
    sWoT[i] = Wo[d * V + v];
  }
  __syncthreads();
}

// ---- kernel C: fused main (t in [3,8), t-major) + prefix-table build ----
__global__ __launch_bounds__(256) void fused_main_kernel(
    const int* __restrict__ tokens,
    float* __restrict__ ws,
    const float* __restrict__ W1, const float* __restrict__ W2,
    const float* __restrict__ Wo, float* __restrict__ out) {
  __shared__ float sW1[D * H];    // 8 KB
  __shared__ float sW2[H * D];    // 8 KB
  __shared__ float sWoT[V * D];   // 3.4 KB
  stage_weights(W1, W2, Wo, sW1, sW2, sWoT);

  if (blockIdx.x < MAIN_BLOCKS) {
    const int idx = blockIdx.x * 256 + threadIdx.x;   // [0, 5*BTOT), exact
    const int t = 3 + (idx >> 17);                    // wave-uniform (BTOT=2^17)
    const int b = idx & (BTOT - 1);
    const int4 ta = *(const int4*)(tokens + b * T);
    const int4 tb = *(const int4*)(tokens + b * T + 4);
    int toks[T];
    toks[0] = ta.x; toks[1] = ta.y; toks[2] = ta.z; toks[3] = ta.w;
    toks[4] = tb.x; toks[5] = tb.y; toks[6] = tb.z; toks[7] = tb.w;
    compute_row(t, toks, ws, sW1, sW2, sWoT, out + (long long)(b * T + t) * V);
  } else {
    const int i = (blockIdx.x - MAIN_BLOCKS) * 256 + threadIdx.x;
    if (i >= NPRE) return;
    int t, p;
    if (i < NPRE0)              { t = 0; p = i; }
    else if (i < NPRE0 + NPRE1) { t = 1; p = i - NPRE0; }
    else                        { t = 2; p = i - NPRE0 - NPRE1; }
    int toks[T] = {0, 0, 0, 0, 0, 0, 0, 0};
    if (t == 0) { toks[0] = p; }
    else if (t == 1) { toks[0] = p / 27; toks[1] = p % 27; }
    else { toks[0] = p / 729; const int r = p % 729; toks[1] = r / 27; toks[2] = r % 27; }
    compute_row(t, toks, ws, sW1, sW2, sWoT, ws + WS_P + i * V);
  }
}

// ---- kernel G: gather t<=2 rows; thread per (b, r) with r in [0,81) so
//      each b's three output rows are one contiguous 324B write run ----
__global__ __launch_bounds__(256) void gather_kernel(
    const int* __restrict__ tokens,
    const float* __restrict__ ws,
    float* __restrict__ out) {
  const int idx = blockIdx.x * 256 + threadIdx.x;   // [0, BTOT*81), exact
  const int b = idx / 81;
  const int r = idx - b * 81;
  const int t = r / 27;
  const int j = r - t * 27;
  const int t0 = tokens[b * T + 0];
  const int t1 = tokens[b * T + 1];
  const int t2 = tokens[b * T + 2];
  const int p01 = t0 * 27 + t1;
  const int pi = (t == 0) ? t0
               : (t == 1) ? (NPRE0 + p01)
                          : (NPRE0 + NPRE1 + p01 * 27 + t2);
  out[(long long)b * (T * V) + r] = ws[WS_P + pi * V + j];
}

// ---- fallback (R4-style): all rows, r-major ----
__global__ __launch_bounds__(256) void mini_kernel_all(
    const int* __restrict__ tokens,
    const float* __restrict__ ws,
    const float* __restrict__ W1, const float* __restrict__ W2,
    const float* __restrict__ Wo, float* __restrict__ out) {
  __shared__ float sW1[D * H];
  __shared__ float sW2[H * D];
  __shared__ float sWoT[V * D];
  stage_weights(W1, W2, Wo, sW1, sW2, sWoT);

  const int r = blockIdx.x * 256 + threadIdx.x;
  const int b = r >> 3;
  const int t = r & 7;
  const int4 ta = *(const int4*)(tokens + b * T);
  const int4 tb = *(const int4*)(tokens + b * T + 4);
  int toks[T];
  toks[0] = ta.x; toks[1] = ta.y; toks[2] = ta.z; toks[3] = ta.w;
  toks[4] = tb.x; toks[5] = tb.y; toks[6] = tb.z; toks[7] = tb.w;
  compute_row(t, toks, ws, sW1, sW2, sWoT, out + (long long)r * V);
}

extern "C" void kernel_launch(void* const* d_in, const int* in_sizes, int n_in,
                              void* d_out, int out_size, void* d_ws, size_t ws_size,
                              hipStream_t stream) {
  const int*   tokens  = (const int*)d_in[0];
  const float* tok_emb = (const float*)d_in[1];
  const float* pos_emb = (const float*)d_in[2];
  const float* Wq      = (const float*)d_in[3];
  const float* Wk      = (const float*)d_in[4];
  const float* Wv      = (const float*)d_in[5];
  const float* W1      = (const float*)d_in[6];
  const float* W2      = (const float*)d_in[7];
  const float* Wout    = (const float*)d_in[8];
  float* ws = (float*)d_ws;
  float* out = (float*)d_out;

  hipLaunchKernelGGL(build_rows_kernel, dim3((NROW * D + 255) / 256), dim3(256), 0,
                     stream, tok_emb, pos_emb, Wq, Wk, Wv, ws);
  hipLaunchKernelGGL(build_sc_kernel, dim3((NSC + 255) / 256), dim3(256), 0, stream, ws);

  if (ws_size >= WS_NEED_BIG) {
    hipLaunchKernelGGL(fused_main_kernel, dim3(MAIN_BLOCKS + PRE_BLOCKS), dim3(256), 0,
                       stream, tokens, ws, W1, W2, Wout, out);
    hipLaunchKernelGGL(gather_kernel, dim3((BTOT * 81) / 256), dim3(256), 0, stream,
                       tokens, ws, out);
  } else {
    hipLaunchKernelGGL(mini_kernel_all, dim3((BTOT * T) / 256), dim3(256), 0,
                       stream, tokens, ws, W1, W2, Wout, out);
  }
}